// Round 12
// baseline (344.670 us; speedup 1.0000x reference)
//
#include <hip/hip_runtime.h>
#include <hip/hip_bf16.h>
#include <math.h>

#define NN 50000
#define NE 800000
#define HD 128
#define NB 196        // coarse buckets: id >> 8  (196*256 = 50176 >= NN)
#define CAP 5120      // per-bucket edge capacity (avg 4082, +16 sigma)
#define B1_EPB 1024   // edges per block in bucket_kernel

typedef __attribute__((ext_vector_type(8))) short bf16x8v;   // 8 bf16 (4 VGPRs)
typedef __attribute__((ext_vector_type(4))) float f32x4v;    // MFMA acc

static __device__ __forceinline__ unsigned short f2bf(float x) {
    union { float f; unsigned u; } v; v.f = x;
    unsigned r = v.u + 0x7fff + ((v.u >> 16) & 1);   // RNE
    return (unsigned short)(r >> 16);
}

// ---------------- B1: coarse bucket scatter (ushort-compressed) ----------------
__global__ __launch_bounds__(256) void bucket_kernel(const int* __restrict__ src,
                                                     const int* __restrict__ dst,
                                                     int* __restrict__ dcur,
                                                     int* __restrict__ scur,
                                                     ushort2* __restrict__ dbucket,
                                                     unsigned short* __restrict__ sbucket) {
    __shared__ int hd[NB], hsb[NB], cd[NB], cs[NB];
    int t = threadIdx.x;
    if (t < NB) { hd[t] = 0; hsb[t] = 0; }
    __syncthreads();
    int d[4], s[4];
    int e0 = blockIdx.x * B1_EPB + t;
    #pragma unroll
    for (int j = 0; j < 4; ++j) {
        int e = e0 + j * 256;
        if (e < NE) {
            d[j] = dst[e]; s[j] = src[e];
            atomicAdd(&hd[d[j] >> 8], 1);
            atomicAdd(&hsb[s[j] >> 8], 1);
        } else d[j] = -1;
    }
    __syncthreads();
    if (t < NB) {
        cd[t] = atomicAdd(&dcur[t], hd[t]);
        cs[t] = atomicAdd(&scur[t], hsb[t]);
    }
    __syncthreads();
    #pragma unroll
    for (int j = 0; j < 4; ++j) {
        if (d[j] >= 0) {
            int b = d[j] >> 8;
            int p = atomicAdd(&cd[b], 1);
            if (p < CAP) dbucket[(long)b * CAP + p] = make_ushort2((unsigned short)d[j],
                                                                   (unsigned short)s[j]);
            int bs = s[j] >> 8;
            int p2 = atomicAdd(&cs[bs], 1);
            if (p2 < CAP) sbucket[(long)bs * CAP + p2] = (unsigned short)s[j];
        }
    }
}

// ---------------- B2+B3 merged: compact CSR (ushort col) + out-degree ----------------
__global__ __launch_bounds__(256) void csr_out_kernel(const ushort2* __restrict__ dbucket,
                                                      const int* __restrict__ dcur,
                                                      const unsigned short* __restrict__ sbucket,
                                                      const int* __restrict__ scur,
                                                      int* __restrict__ row_ptr,
                                                      unsigned short* __restrict__ col,
                                                      int* __restrict__ out_cnt) {
    __shared__ int buf[256];
    __shared__ int hist[256];
    __shared__ int cur[256];
    int k = blockIdx.x, t = threadIdx.x;

    int tot = (t < NB) ? min(dcur[t], CAP) : 0;
    buf[t] = tot;
    __syncthreads();
    for (int o = 1; o < 256; o <<= 1) {
        int a = (t >= o) ? buf[t - o] : 0;
        __syncthreads();
        buf[t] += a;
        __syncthreads();
    }
    int base = (k > 0) ? buf[k - 1] : 0;
    int cnt = min(dcur[k], CAP);

    hist[t] = 0;
    __syncthreads();
    const ushort2* bk = dbucket + (long)k * CAP;
    for (int e = t; e < cnt; e += 256) atomicAdd(&hist[bk[e].x & 255], 1);
    __syncthreads();
    int h = hist[t];

    buf[t] = h;
    __syncthreads();
    for (int o = 1; o < 256; o <<= 1) {
        int a = (t >= o) ? buf[t - o] : 0;
        __syncthreads();
        buf[t] += a;
        __syncthreads();
    }
    int start = base + buf[t] - h;
    int id = (k << 8) + t;
    if (id < NN) row_ptr[id] = start;
    if (k == NB - 1 && t == 0) row_ptr[NN] = base + cnt;
    cur[t] = start;
    __syncthreads();

    for (int e = t; e < cnt; e += 256) {
        ushort2 p = bk[e];
        int pos = atomicAdd(&cur[p.x & 255], 1);
        col[pos] = p.y;
    }

    __syncthreads();
    hist[t] = 0;
    __syncthreads();
    int scnt = min(scur[k], CAP);
    const unsigned short* sk = sbucket + (long)k * CAP;
    for (int e = t; e < scnt; e += 256) atomicAdd(&hist[sk[e] & 255], 1);
    __syncthreads();
    if (id < NN) out_cnt[id] = hist[t];
}

// ---------------- merged node init + weight convert + embsum zero ----------------
__global__ __launch_bounds__(256) void initw_kernel(const float* __restrict__ cx,
                                                    const float* __restrict__ cy,
                                                    const int* __restrict__ row_ptr,
                                                    const int* __restrict__ out_cnt,
                                                    const float* __restrict__ W2,
                                                    const float* __restrict__ W3,
                                                    const float* __restrict__ W4,
                                                    const float* __restrict__ W5,
                                                    float* __restrict__ norm_s,
                                                    float* __restrict__ norm_d,
                                                    float* __restrict__ h0s,
                                                    unsigned short* __restrict__ Wt,
                                                    float* __restrict__ embsum) {
    int bid = blockIdx.x, t = threadIdx.x;
    if (bid < NB) {
        int i = (bid << 8) + t;
        if (i < NN) {
            float id = (float)(row_ptr[i + 1] - row_ptr[i]);
            float od = (float)out_cnt[i];
            float ns = 1.0f / sqrtf(fmaxf(od, 1.0f));
            norm_s[i] = ns;
            norm_d[i] = 1.0f / sqrtf(fmaxf(id, 1.0f));
            h0s[i * 3 + 0] = id * ns;
            h0s[i * 3 + 1] = cx[i] * ns;
            h0s[i * 3 + 2] = cy[i] * ns;
        }
    } else {
        int gid = ((bid - NB) << 8) + t;     // < 65536
        int l = gid >> 14, idx = gid & 16383;
        int n = idx >> 7, k = idx & 127;
        const float* W = (l == 0) ? W2 : (l == 1) ? W3 : (l == 2) ? W4 : W5;
        Wt[gid] = f2bf(W[k * 128 + n]);
        if (bid == NB && t < 128) embsum[t] = 0.0f;
    }
}

// ---------------- layer 1 fused: gather (F=3) + 3->128 matvec, one kernel ----------------
// 256 nodes/block. Phase A: thread t gathers node n0+t into LDS. Phase B:
// (node,col) sweep from LDS-staged A + W1.
__global__ __launch_bounds__(256) void layer1_kernel(const int* __restrict__ row_ptr,
                                                     const unsigned short* __restrict__ col,
                                                     const float* __restrict__ h0s,
                                                     const float* __restrict__ norm_d,
                                                     const float* __restrict__ norm_s,
                                                     const float* __restrict__ W1,
                                                     const float* __restrict__ b1,
                                                     unsigned short* __restrict__ h1s) {
    __shared__ float la3[256][3];
    __shared__ float lw[3][128];
    __shared__ float lb[128];
    int t = threadIdx.x;
    int n0 = blockIdx.x << 8;
    if (t < 128) {
        lw[0][t] = W1[t]; lw[1][t] = W1[128 + t]; lw[2][t] = W1[256 + t];
        lb[t] = b1[t];
    }
    int n = n0 + t;
    if (n < NN) {
        float a0 = 0.f, a1 = 0.f, a2 = 0.f;
        int end = row_ptr[n + 1];
        for (int e = row_ptr[n]; e < end; ++e) {
            int s = col[e];
            a0 += h0s[s * 3 + 0];
            a1 += h0s[s * 3 + 1];
            a2 += h0s[s * 3 + 2];
        }
        float nd = norm_d[n];
        la3[t][0] = a0 * nd; la3[t][1] = a1 * nd; la3[t][2] = a2 * nd;
    }
    __syncthreads();
    #pragma unroll 4
    for (int i = 0; i < 128; ++i) {
        int idx = (i << 8) + t;
        int r = idx >> 7, c = idx & 127;
        int nn = n0 + r;
        if (nn < NN) {
            float v = la3[r][0] * lw[0][c] + la3[r][1] * lw[1][c]
                    + la3[r][2] * lw[2][c] + lb[c];
            h1s[((long)nn << 7) + c] = f2bf(fmaxf(v, 0.f) * norm_s[nn]);
        }
    }
}

// ---------------- FUSED layer (2..5): work-steal gather -> LDS -> MFMA ----------------
// 16 nodes/block, 4 waves. Rows claimed via LDS cursor (wave balance). Gather
// unroll-16 (16 loads in flight). B-frags direct from L2-hot Wt. Hidden layers:
// bf16 out scaled by norm_s. Last layer (out_f32 != null): fp32 out + colsum.
__global__ __launch_bounds__(256) void fused_layer16_kernel(const int* __restrict__ row_ptr,
                                                            const unsigned short* __restrict__ col,
                                                            const unsigned int* __restrict__ hin,
                                                            const float* __restrict__ norm_d,
                                                            const float* __restrict__ norm_s,
                                                            const unsigned short* __restrict__ Wt,
                                                            const float* __restrict__ bias,
                                                            unsigned short* __restrict__ hout,
                                                            float* __restrict__ out_f32,
                                                            float* __restrict__ embsum) {
    __shared__ unsigned int lA[16][68];   // bf16x2 A-tile; stride 68 dw -> 2-way banks (free)
    __shared__ float ldscol[4][128];
    __shared__ int cursor;
    int t = threadIdx.x;
    int wv = t >> 6, lane = t & 63;
    int m0 = blockIdx.x << 4;             // 3125 blocks x 16 nodes == 50000 exactly

    if (t == 0) cursor = 0;
    __syncthreads();

    // ---- gather phase: waves steal rows from the block cursor ----
    const unsigned int* hb = hin + lane;
    for (;;) {
        int r0 = 0;
        if (lane == 0) r0 = atomicAdd(&cursor, 1);
        int r = __shfl(r0, 0);
        if (r >= 16) break;
        int n = m0 + r;
        int beg = row_ptr[n], end = row_ptr[n + 1];
        float nd = norm_d[n];
        float ax = 0.f, ay = 0.f;
        int e = beg;
        for (; e + 15 < end; e += 16) {
            unsigned u[16];
            #pragma unroll
            for (int j = 0; j < 16; ++j) u[j] = hb[(long)col[e + j] << 6];
            #pragma unroll
            for (int j = 0; j < 16; ++j) {
                ax += __uint_as_float(u[j] << 16);
                ay += __uint_as_float(u[j] & 0xffff0000u);
            }
        }
        for (; e + 7 < end; e += 8) {
            unsigned u[8];
            #pragma unroll
            for (int j = 0; j < 8; ++j) u[j] = hb[(long)col[e + j] << 6];
            #pragma unroll
            for (int j = 0; j < 8; ++j) {
                ax += __uint_as_float(u[j] << 16);
                ay += __uint_as_float(u[j] & 0xffff0000u);
            }
        }
        for (; e < end; ++e) {
            unsigned u0 = hb[(long)col[e] << 6];
            ax += __uint_as_float(u0 << 16);
            ay += __uint_as_float(u0 & 0xffff0000u);
        }
        lA[r][lane] = (unsigned)f2bf(ax * nd) | ((unsigned)f2bf(ay * nd) << 16);
    }
    __syncthreads();

    // ---- GEMM phase: wave wv computes cols [wv*32, wv*32+32) ----
    int fr = lane & 15, kq = lane >> 4;
    bf16x8v a0 = *(const bf16x8v*)&lA[fr][ 0 + (kq << 2)];
    bf16x8v a1 = *(const bf16x8v*)&lA[fr][16 + (kq << 2)];
    bf16x8v a2 = *(const bf16x8v*)&lA[fr][32 + (kq << 2)];
    bf16x8v a3 = *(const bf16x8v*)&lA[fr][48 + (kq << 2)];

    float4 scv = make_float4(1.f, 1.f, 1.f, 1.f);
    if (!out_f32) scv = *(const float4*)(norm_s + m0 + (kq << 2));

    #pragma unroll
    for (int j = 0; j < 2; ++j) {
        int n0 = ((wv << 1) + j) << 4;
        const unsigned short* wb = Wt + ((n0 + fr) << 7) + (kq << 3);
        f32x4v acc = {0.f, 0.f, 0.f, 0.f};
        acc = __builtin_amdgcn_mfma_f32_16x16x32_bf16(a0, *(const bf16x8v*)(wb + 0),  acc, 0, 0, 0);
        acc = __builtin_amdgcn_mfma_f32_16x16x32_bf16(a1, *(const bf16x8v*)(wb + 32), acc, 0, 0, 0);
        acc = __builtin_amdgcn_mfma_f32_16x16x32_bf16(a2, *(const bf16x8v*)(wb + 64), acc, 0, 0, 0);
        acc = __builtin_amdgcn_mfma_f32_16x16x32_bf16(a3, *(const bf16x8v*)(wb + 96), acc, 0, 0, 0);

        int c = n0 + fr;
        float bv = bias[c];
        if (out_f32) {
            float cs = 0.f;
            #pragma unroll
            for (int r = 0; r < 4; ++r) {
                int mr = m0 + (kq << 2) + r;
                float v = fmaxf(acc[r] + bv, 0.f);
                out_f32[((long)mr << 7) + c] = v;
                cs += v;
            }
            ldscol[kq][c] = cs;   // slot (kq,c) unique across block
        } else {
            #pragma unroll
            for (int r = 0; r < 4; ++r) {
                int mr = m0 + (kq << 2) + r;
                float v = fmaxf(acc[r] + bv, 0.f);
                float sc = (r == 0) ? scv.x : (r == 1) ? scv.y : (r == 2) ? scv.z : scv.w;
                hout[((long)mr << 7) + c] = f2bf(v * sc);
            }
        }
    }

    if (out_f32) {
        __syncthreads();
        if (t < 128) {
            float s = ldscol[0][t] + ldscol[1][t] + ldscol[2][t] + ldscol[3][t];
            atomicAdd(&embsum[t], s);
        }
    }
}

// ---------------- head MLP ----------------
__global__ __launch_bounds__(128) void head_kernel(const float* __restrict__ embsum,
                                                   const float* __restrict__ Wl1,
                                                   const float* __restrict__ bl1,
                                                   const float* __restrict__ Wl2,
                                                   const float* __restrict__ bl2,
                                                   float* __restrict__ d_out) {
    __shared__ float emb[128];
    __shared__ float hemb[64];
    int t = threadIdx.x;
    float e = embsum[t] * (1.0f / (float)NN);
    emb[t] = e;
    d_out[1 + t] = e;
    __syncthreads();
    if (t < 64) {
        float acc = bl1[t];
        for (int k = 0; k < 128; ++k)
            acc += emb[k] * Wl1[k * 64 + t];
        hemb[t] = fmaxf(acc, 0.f);
    }
    __syncthreads();
    if (t == 0) {
        float acc = bl2[0];
        for (int j = 0; j < 64; ++j)
            acc += hemb[j] * Wl2[j];
        d_out[0] = 1.0f / (1.0f + expf(-acc));
    }
}

extern "C" void kernel_launch(void* const* d_in, const int* in_sizes, int n_in,
                              void* d_out, int out_size, void* d_ws, size_t ws_size,
                              hipStream_t stream) {
    const float* cx  = (const float*)d_in[0];
    const float* cy  = (const float*)d_in[1];
    const float* W1  = (const float*)d_in[2];
    const float* b1  = (const float*)d_in[3];
    const float* W2  = (const float*)d_in[4];
    const float* b2  = (const float*)d_in[5];
    const float* W3  = (const float*)d_in[6];
    const float* b3  = (const float*)d_in[7];
    const float* W4  = (const float*)d_in[8];
    const float* b4  = (const float*)d_in[9];
    const float* W5  = (const float*)d_in[10];
    const float* b5  = (const float*)d_in[11];
    const float* Wl1 = (const float*)d_in[12];
    const float* bl1 = (const float*)d_in[13];
    const float* Wl2 = (const float*)d_in[14];
    const float* bl2 = (const float*)d_in[15];
    const int*   src = (const int*)d_in[16];
    const int*   dst = (const int*)d_in[17];

    float* out = (float*)d_out;
    float* h_out = out + 129;

    // workspace layout (float-index units)
    float* ws       = (float*)d_ws;
    float* norm_s   = ws;                                   // N
    float* norm_d   = ws + NN;                              // N
    int*   out_cnt  = (int*)(ws + 2 * NN);                  // N
    int*   row_ptr  = (int*)(ws + 3 * NN);                  // N+1
    unsigned short* hsA = (unsigned short*)(ws + 4 * NN + 64);    // 128N bf16
    unsigned short* hsB = (unsigned short*)(ws + 68 * NN + 64);   // 128N bf16
    unsigned short* col = (unsigned short*)(ws + 132 * NN + 64);  // NE ushort
    float* h0s      = ws + 148 * NN + 64;                   // 3N
    unsigned short* Wt = (unsigned short*)(ws + 154 * NN + 64);   // 4*16384 bf16
    float* embsum   = ws + 154 * NN + 64 + 32768;           // 128
    int*   dcur     = (int*)(ws + 154 * NN + 33600);        // NB
    int*   scur     = dcur + NB;                            // NB
    ushort2* dbucket = (ushort2*)(ws + 154 * NN + 34048);   // NB*CAP ushort2
    unsigned short* sbucket = (unsigned short*)(ws + 154 * NN + 34048 + NB * CAP);

    // 1. two-level bucket CSR build (atomic-light, ushort-compressed)
    hipMemsetAsync(dcur, 0, 2 * NB * sizeof(int), stream);
    bucket_kernel<<<(NE + B1_EPB - 1) / B1_EPB, 256, 0, stream>>>(src, dst, dcur, scur,
                                                                  dbucket, sbucket);
    csr_out_kernel<<<NB, 256, 0, stream>>>(dbucket, dcur, sbucket, scur,
                                           row_ptr, col, out_cnt);

    // 2. norms + scaled h0 + weight convert + embsum zero (merged)
    initw_kernel<<<NB + 256, 256, 0, stream>>>(cx, cy, row_ptr, out_cnt,
                                               W2, W3, W4, W5,
                                               norm_s, norm_d, h0s, Wt, embsum);

    // 3. layer 1 (F_in = 3), single fused kernel -> hsA
    layer1_kernel<<<(NN + 255) / 256, 256, 0, stream>>>(row_ptr, col, h0s,
                                                        norm_d, norm_s, W1, b1, hsA);

    // 4. layers 2..5: fused work-steal gather + MFMA; ping-pong hsA/hsB; last -> d_out
    const float* bs[4] = {b2, b3, b4, b5};
    unsigned short* hcur = hsA;
    unsigned short* hnxt = hsB;
    for (int l = 0; l < 4; ++l) {
        bool last = (l == 3);
        fused_layer16_kernel<<<NN / 16, 256, 0, stream>>>(
            row_ptr, col, (const unsigned int*)hcur, norm_d, norm_s,
            Wt + l * 16384, bs[l],
            last ? nullptr : hnxt,
            last ? h_out : nullptr,
            last ? embsum : nullptr);
        unsigned short* tmp = hcur; hcur = hnxt; hnxt = tmp;
    }

    // 5. head
    head_kernel<<<1, 128, 0, stream>>>(embsum, Wl1, bl1, Wl2, bl2, out);
}

// Round 13
// 329.683 us; speedup vs baseline: 1.0455x; 1.0455x over previous
//
#include <hip/hip_runtime.h>
#include <hip/hip_bf16.h>
#include <math.h>

#define NN 50000
#define NE 800000
#define HD 128
#define NB 196        // coarse buckets: id >> 8  (196*256 = 50176 >= NN)
#define CAP 5120      // per-bucket edge capacity (avg 4082, +16 sigma)
#define B1_EPB 1024   // edges per block in bucket_kernel

typedef __attribute__((ext_vector_type(8))) short bf16x8v;   // 8 bf16 (4 VGPRs)
typedef __attribute__((ext_vector_type(4))) float f32x4v;    // MFMA acc

static __device__ __forceinline__ unsigned short f2bf(float x) {
    union { float f; unsigned u; } v; v.f = x;
    unsigned r = v.u + 0x7fff + ((v.u >> 16) & 1);   // RNE
    return (unsigned short)(r >> 16);
}

// ---------------- B1: coarse bucket scatter (ushort-compressed) ----------------
__global__ __launch_bounds__(256) void bucket_kernel(const int* __restrict__ src,
                                                     const int* __restrict__ dst,
                                                     int* __restrict__ dcur,
                                                     int* __restrict__ scur,
                                                     ushort2* __restrict__ dbucket,
                                                     unsigned short* __restrict__ sbucket) {
    __shared__ int hd[NB], hsb[NB], cd[NB], cs[NB];
    int t = threadIdx.x;
    if (t < NB) { hd[t] = 0; hsb[t] = 0; }
    __syncthreads();
    int d[4], s[4];
    int e0 = blockIdx.x * B1_EPB + t;
    #pragma unroll
    for (int j = 0; j < 4; ++j) {
        int e = e0 + j * 256;
        if (e < NE) {
            d[j] = dst[e]; s[j] = src[e];
            atomicAdd(&hd[d[j] >> 8], 1);
            atomicAdd(&hsb[s[j] >> 8], 1);
        } else d[j] = -1;
    }
    __syncthreads();
    if (t < NB) {
        cd[t] = atomicAdd(&dcur[t], hd[t]);
        cs[t] = atomicAdd(&scur[t], hsb[t]);
    }
    __syncthreads();
    #pragma unroll
    for (int j = 0; j < 4; ++j) {
        if (d[j] >= 0) {
            int b = d[j] >> 8;
            int p = atomicAdd(&cd[b], 1);
            if (p < CAP) dbucket[(long)b * CAP + p] = make_ushort2((unsigned short)d[j],
                                                                   (unsigned short)s[j]);
            int bs = s[j] >> 8;
            int p2 = atomicAdd(&cs[bs], 1);
            if (p2 < CAP) sbucket[(long)bs * CAP + p2] = (unsigned short)s[j];
        }
    }
}

// ---------------- B2+B3 merged: compact CSR (ushort col) + out-degree ----------------
__global__ __launch_bounds__(256) void csr_out_kernel(const ushort2* __restrict__ dbucket,
                                                      const int* __restrict__ dcur,
                                                      const unsigned short* __restrict__ sbucket,
                                                      const int* __restrict__ scur,
                                                      int* __restrict__ row_ptr,
                                                      unsigned short* __restrict__ col,
                                                      int* __restrict__ out_cnt) {
    __shared__ int buf[256];
    __shared__ int hist[256];
    __shared__ int cur[256];
    int k = blockIdx.x, t = threadIdx.x;

    int tot = (t < NB) ? min(dcur[t], CAP) : 0;
    buf[t] = tot;
    __syncthreads();
    for (int o = 1; o < 256; o <<= 1) {
        int a = (t >= o) ? buf[t - o] : 0;
        __syncthreads();
        buf[t] += a;
        __syncthreads();
    }
    int base = (k > 0) ? buf[k - 1] : 0;
    int cnt = min(dcur[k], CAP);

    hist[t] = 0;
    __syncthreads();
    const ushort2* bk = dbucket + (long)k * CAP;
    for (int e = t; e < cnt; e += 256) atomicAdd(&hist[bk[e].x & 255], 1);
    __syncthreads();
    int h = hist[t];

    buf[t] = h;
    __syncthreads();
    for (int o = 1; o < 256; o <<= 1) {
        int a = (t >= o) ? buf[t - o] : 0;
        __syncthreads();
        buf[t] += a;
        __syncthreads();
    }
    int start = base + buf[t] - h;
    int id = (k << 8) + t;
    if (id < NN) row_ptr[id] = start;
    if (k == NB - 1 && t == 0) row_ptr[NN] = base + cnt;
    cur[t] = start;
    __syncthreads();

    for (int e = t; e < cnt; e += 256) {
        ushort2 p = bk[e];
        int pos = atomicAdd(&cur[p.x & 255], 1);
        col[pos] = p.y;
    }

    __syncthreads();
    hist[t] = 0;
    __syncthreads();
    int scnt = min(scur[k], CAP);
    const unsigned short* sk = sbucket + (long)k * CAP;
    for (int e = t; e < scnt; e += 256) atomicAdd(&hist[sk[e] & 255], 1);
    __syncthreads();
    if (id < NN) out_cnt[id] = hist[t];
}

// ---------------- merged node init + weight convert + embsum zero ----------------
__global__ __launch_bounds__(256) void initw_kernel(const float* __restrict__ cx,
                                                    const float* __restrict__ cy,
                                                    const int* __restrict__ row_ptr,
                                                    const int* __restrict__ out_cnt,
                                                    const float* __restrict__ W2,
                                                    const float* __restrict__ W3,
                                                    const float* __restrict__ W4,
                                                    const float* __restrict__ W5,
                                                    float* __restrict__ norm_s,
                                                    float* __restrict__ norm_d,
                                                    float* __restrict__ h0s,
                                                    unsigned short* __restrict__ Wt,
                                                    float* __restrict__ embsum) {
    int bid = blockIdx.x, t = threadIdx.x;
    if (bid < NB) {
        int i = (bid << 8) + t;
        if (i < NN) {
            float id = (float)(row_ptr[i + 1] - row_ptr[i]);
            float od = (float)out_cnt[i];
            float ns = 1.0f / sqrtf(fmaxf(od, 1.0f));
            norm_s[i] = ns;
            norm_d[i] = 1.0f / sqrtf(fmaxf(id, 1.0f));
            h0s[i * 3 + 0] = id * ns;
            h0s[i * 3 + 1] = cx[i] * ns;
            h0s[i * 3 + 2] = cy[i] * ns;
        }
    } else {
        int gid = ((bid - NB) << 8) + t;     // < 65536
        int l = gid >> 14, idx = gid & 16383;
        int n = idx >> 7, k = idx & 127;
        const float* W = (l == 0) ? W2 : (l == 1) ? W3 : (l == 2) ? W4 : W5;
        Wt[gid] = f2bf(W[k * 128 + n]);
        if (bid == NB && t < 128) embsum[t] = 0.0f;
    }
}

// ---------------- layer 1 fused: gather (F=3) + 3->128 matvec, one kernel ----------------
__global__ __launch_bounds__(256) void layer1_kernel(const int* __restrict__ row_ptr,
                                                     const unsigned short* __restrict__ col,
                                                     const float* __restrict__ h0s,
                                                     const float* __restrict__ norm_d,
                                                     const float* __restrict__ norm_s,
                                                     const float* __restrict__ W1,
                                                     const float* __restrict__ b1,
                                                     unsigned short* __restrict__ h1s) {
    __shared__ float la3[256][3];
    __shared__ float lw[3][128];
    __shared__ float lb[128];
    int t = threadIdx.x;
    int n0 = blockIdx.x << 8;
    if (t < 128) {
        lw[0][t] = W1[t]; lw[1][t] = W1[128 + t]; lw[2][t] = W1[256 + t];
        lb[t] = b1[t];
    }
    int n = n0 + t;
    if (n < NN) {
        float a0 = 0.f, a1 = 0.f, a2 = 0.f;
        int end = row_ptr[n + 1];
        for (int e = row_ptr[n]; e < end; ++e) {
            int s = col[e];
            a0 += h0s[s * 3 + 0];
            a1 += h0s[s * 3 + 1];
            a2 += h0s[s * 3 + 2];
        }
        float nd = norm_d[n];
        la3[t][0] = a0 * nd; la3[t][1] = a1 * nd; la3[t][2] = a2 * nd;
    }
    __syncthreads();
    #pragma unroll 4
    for (int i = 0; i < 128; ++i) {
        int idx = (i << 8) + t;
        int r = idx >> 7, c = idx & 127;
        int nn = n0 + r;
        if (nn < NN) {
            float v = la3[r][0] * lw[0][c] + la3[r][1] * lw[1][c]
                    + la3[r][2] * lw[2][c] + lb[c];
            h1s[((long)nn << 7) + c] = f2bf(fmaxf(v, 0.f) * norm_s[nn]);
        }
    }
}

// ---------------- FUSED layer (2..5): paired dual-stream gather -> LDS -> MFMA ----------
// 16 nodes/block, 4 waves. Wave wv statically owns row pairs {wv,4+wv} then
// {8+wv,12+wv}; each pair's edge lists are walked SIMULTANEOUSLY (two
// independent 4-deep load chains = 8 loads in flight, no spill at ~48 VGPR).
// B-frags direct from L2-hot Wt. Hidden: bf16 out scaled by norm_s.
// Last layer (out_f32 != null): fp32 out + fused colsum.
__global__ __launch_bounds__(256) void fused_layer16_kernel(const int* __restrict__ row_ptr,
                                                            const unsigned short* __restrict__ col,
                                                            const unsigned int* __restrict__ hin,
                                                            const float* __restrict__ norm_d,
                                                            const float* __restrict__ norm_s,
                                                            const unsigned short* __restrict__ Wt,
                                                            const float* __restrict__ bias,
                                                            unsigned short* __restrict__ hout,
                                                            float* __restrict__ out_f32,
                                                            float* __restrict__ embsum) {
    __shared__ unsigned int lA[16][68];   // bf16x2 A-tile; stride 68 dw -> 2-way banks (free)
    __shared__ float ldscol[4][128];
    int t = threadIdx.x;
    int wv = t >> 6, lane = t & 63;
    int m0 = blockIdx.x << 4;             // 3125 blocks x 16 nodes == 50000 exactly

    const unsigned int* hb = hin + lane;
    #pragma unroll
    for (int half = 0; half < 2; ++half) {
        int rA = (half << 3) + wv;        // wv, 8+wv
        int rB = rA + 4;                  // 4+wv, 12+wv
        int nA = m0 + rA, nB = m0 + rB;
        int eA = row_ptr[nA], endA = row_ptr[nA + 1];
        int eB = row_ptr[nB], endB = row_ptr[nB + 1];
        float axA = 0.f, ayA = 0.f, axB = 0.f, ayB = 0.f;

        // dual-stream main loop: 8 independent loads in flight
        while (eA + 3 < endA && eB + 3 < endB) {
            unsigned uA[4], uB[4];
            #pragma unroll
            for (int j = 0; j < 4; ++j) uA[j] = hb[(long)col[eA + j] << 6];
            #pragma unroll
            for (int j = 0; j < 4; ++j) uB[j] = hb[(long)col[eB + j] << 6];
            #pragma unroll
            for (int j = 0; j < 4; ++j) {
                axA += __uint_as_float(uA[j] << 16);
                ayA += __uint_as_float(uA[j] & 0xffff0000u);
                axB += __uint_as_float(uB[j] << 16);
                ayB += __uint_as_float(uB[j] & 0xffff0000u);
            }
            eA += 4; eB += 4;
        }
        // drain A
        for (; eA + 3 < endA; eA += 4) {
            unsigned u[4];
            #pragma unroll
            for (int j = 0; j < 4; ++j) u[j] = hb[(long)col[eA + j] << 6];
            #pragma unroll
            for (int j = 0; j < 4; ++j) {
                axA += __uint_as_float(u[j] << 16);
                ayA += __uint_as_float(u[j] & 0xffff0000u);
            }
        }
        for (; eA < endA; ++eA) {
            unsigned u0 = hb[(long)col[eA] << 6];
            axA += __uint_as_float(u0 << 16);
            ayA += __uint_as_float(u0 & 0xffff0000u);
        }
        // drain B
        for (; eB + 3 < endB; eB += 4) {
            unsigned u[4];
            #pragma unroll
            for (int j = 0; j < 4; ++j) u[j] = hb[(long)col[eB + j] << 6];
            #pragma unroll
            for (int j = 0; j < 4; ++j) {
                axB += __uint_as_float(u[j] << 16);
                ayB += __uint_as_float(u[j] & 0xffff0000u);
            }
        }
        for (; eB < endB; ++eB) {
            unsigned u0 = hb[(long)col[eB] << 6];
            axB += __uint_as_float(u0 << 16);
            ayB += __uint_as_float(u0 & 0xffff0000u);
        }

        float ndA = norm_d[nA], ndB = norm_d[nB];
        lA[rA][lane] = (unsigned)f2bf(axA * ndA) | ((unsigned)f2bf(ayA * ndA) << 16);
        lA[rB][lane] = (unsigned)f2bf(axB * ndB) | ((unsigned)f2bf(ayB * ndB) << 16);
    }
    __syncthreads();

    // ---- GEMM phase: wave wv computes cols [wv*32, wv*32+32) ----
    int fr = lane & 15, kq = lane >> 4;
    bf16x8v a0 = *(const bf16x8v*)&lA[fr][ 0 + (kq << 2)];
    bf16x8v a1 = *(const bf16x8v*)&lA[fr][16 + (kq << 2)];
    bf16x8v a2 = *(const bf16x8v*)&lA[fr][32 + (kq << 2)];
    bf16x8v a3 = *(const bf16x8v*)&lA[fr][48 + (kq << 2)];

    float4 scv = make_float4(1.f, 1.f, 1.f, 1.f);
    if (!out_f32) scv = *(const float4*)(norm_s + m0 + (kq << 2));

    #pragma unroll
    for (int j = 0; j < 2; ++j) {
        int n0 = ((wv << 1) + j) << 4;
        const unsigned short* wb = Wt + ((n0 + fr) << 7) + (kq << 3);
        f32x4v acc = {0.f, 0.f, 0.f, 0.f};
        acc = __builtin_amdgcn_mfma_f32_16x16x32_bf16(a0, *(const bf16x8v*)(wb + 0),  acc, 0, 0, 0);
        acc = __builtin_amdgcn_mfma_f32_16x16x32_bf16(a1, *(const bf16x8v*)(wb + 32), acc, 0, 0, 0);
        acc = __builtin_amdgcn_mfma_f32_16x16x32_bf16(a2, *(const bf16x8v*)(wb + 64), acc, 0, 0, 0);
        acc = __builtin_amdgcn_mfma_f32_16x16x32_bf16(a3, *(const bf16x8v*)(wb + 96), acc, 0, 0, 0);

        int c = n0 + fr;
        float bv = bias[c];
        if (out_f32) {
            float cs = 0.f;
            #pragma unroll
            for (int r = 0; r < 4; ++r) {
                int mr = m0 + (kq << 2) + r;
                float v = fmaxf(acc[r] + bv, 0.f);
                out_f32[((long)mr << 7) + c] = v;
                cs += v;
            }
            ldscol[kq][c] = cs;   // slot (kq,c) unique across block
        } else {
            #pragma unroll
            for (int r = 0; r < 4; ++r) {
                int mr = m0 + (kq << 2) + r;
                float v = fmaxf(acc[r] + bv, 0.f);
                float sc = (r == 0) ? scv.x : (r == 1) ? scv.y : (r == 2) ? scv.z : scv.w;
                hout[((long)mr << 7) + c] = f2bf(v * sc);
            }
        }
    }

    if (out_f32) {
        __syncthreads();
        if (t < 128) {
            float s = ldscol[0][t] + ldscol[1][t] + ldscol[2][t] + ldscol[3][t];
            atomicAdd(&embsum[t], s);
        }
    }
}

// ---------------- head MLP ----------------
__global__ __launch_bounds__(128) void head_kernel(const float* __restrict__ embsum,
                                                   const float* __restrict__ Wl1,
                                                   const float* __restrict__ bl1,
                                                   const float* __restrict__ Wl2,
                                                   const float* __restrict__ bl2,
                                                   float* __restrict__ d_out) {
    __shared__ float emb[128];
    __shared__ float hemb[64];
    int t = threadIdx.x;
    float e = embsum[t] * (1.0f / (float)NN);
    emb[t] = e;
    d_out[1 + t] = e;
    __syncthreads();
    if (t < 64) {
        float acc = bl1[t];
        for (int k = 0; k < 128; ++k)
            acc += emb[k] * Wl1[k * 64 + t];
        hemb[t] = fmaxf(acc, 0.f);
    }
    __syncthreads();
    if (t == 0) {
        float acc = bl2[0];
        for (int j = 0; j < 64; ++j)
            acc += hemb[j] * Wl2[j];
        d_out[0] = 1.0f / (1.0f + expf(-acc));
    }
}

extern "C" void kernel_launch(void* const* d_in, const int* in_sizes, int n_in,
                              void* d_out, int out_size, void* d_ws, size_t ws_size,
                              hipStream_t stream) {
    const float* cx  = (const float*)d_in[0];
    const float* cy  = (const float*)d_in[1];
    const float* W1  = (const float*)d_in[2];
    const float* b1  = (const float*)d_in[3];
    const float* W2  = (const float*)d_in[4];
    const float* b2  = (const float*)d_in[5];
    const float* W3  = (const float*)d_in[6];
    const float* b3  = (const float*)d_in[7];
    const float* W4  = (const float*)d_in[8];
    const float* b4  = (const float*)d_in[9];
    const float* W5  = (const float*)d_in[10];
    const float* b5  = (const float*)d_in[11];
    const float* Wl1 = (const float*)d_in[12];
    const float* bl1 = (const float*)d_in[13];
    const float* Wl2 = (const float*)d_in[14];
    const float* bl2 = (const float*)d_in[15];
    const int*   src = (const int*)d_in[16];
    const int*   dst = (const int*)d_in[17];

    float* out = (float*)d_out;
    float* h_out = out + 129;

    // workspace layout (float-index units)
    float* ws       = (float*)d_ws;
    float* norm_s   = ws;                                   // N
    float* norm_d   = ws + NN;                              // N
    int*   out_cnt  = (int*)(ws + 2 * NN);                  // N
    int*   row_ptr  = (int*)(ws + 3 * NN);                  // N+1
    unsigned short* hsA = (unsigned short*)(ws + 4 * NN + 64);    // 128N bf16
    unsigned short* hsB = (unsigned short*)(ws + 68 * NN + 64);   // 128N bf16
    unsigned short* col = (unsigned short*)(ws + 132 * NN + 64);  // NE ushort
    float* h0s      = ws + 148 * NN + 64;                   // 3N
    unsigned short* Wt = (unsigned short*)(ws + 154 * NN + 64);   // 4*16384 bf16
    float* embsum   = ws + 154 * NN + 64 + 32768;           // 128
    int*   dcur     = (int*)(ws + 154 * NN + 33600);        // NB
    int*   scur     = dcur + NB;                            // NB
    ushort2* dbucket = (ushort2*)(ws + 154 * NN + 34048);   // NB*CAP ushort2
    unsigned short* sbucket = (unsigned short*)(ws + 154 * NN + 34048 + NB * CAP);

    // 1. two-level bucket CSR build (atomic-light, ushort-compressed)
    hipMemsetAsync(dcur, 0, 2 * NB * sizeof(int), stream);
    bucket_kernel<<<(NE + B1_EPB - 1) / B1_EPB, 256, 0, stream>>>(src, dst, dcur, scur,
                                                                  dbucket, sbucket);
    csr_out_kernel<<<NB, 256, 0, stream>>>(dbucket, dcur, sbucket, scur,
                                           row_ptr, col, out_cnt);

    // 2. norms + scaled h0 + weight convert + embsum zero (merged)
    initw_kernel<<<NB + 256, 256, 0, stream>>>(cx, cy, row_ptr, out_cnt,
                                               W2, W3, W4, W5,
                                               norm_s, norm_d, h0s, Wt, embsum);

    // 3. layer 1 (F_in = 3), single fused kernel -> hsA
    layer1_kernel<<<(NN + 255) / 256, 256, 0, stream>>>(row_ptr, col, h0s,
                                                        norm_d, norm_s, W1, b1, hsA);

    // 4. layers 2..5: fused paired-gather + MFMA; ping-pong hsA/hsB; last -> d_out
    const float* bs[4] = {b2, b3, b4, b5};
    unsigned short* hcur = hsA;
    unsigned short* hnxt = hsB;
    for (int l = 0; l < 4; ++l) {
        bool last = (l == 3);
        fused_layer16_kernel<<<NN / 16, 256, 0, stream>>>(
            row_ptr, col, (const unsigned int*)hcur, norm_d, norm_s,
            Wt + l * 16384, bs[l],
            last ? nullptr : hnxt,
            last ? h_out : nullptr,
            last ? embsum : nullptr);
        unsigned short* tmp = hcur; hcur = hnxt; hnxt = tmp;
    }

    // 5. head
    head_kernel<<<1, 128, 0, stream>>>(embsum, Wl1, bl1, Wl2, bl2, out);
}

// Round 14
// 287.273 us; speedup vs baseline: 1.1998x; 1.1476x over previous
//
#include <hip/hip_runtime.h>
#include <hip/hip_bf16.h>
#include <math.h>

#define NN 50000
#define NE 800000
#define HD 128
#define NB 196        // coarse buckets: id >> 8  (196*256 = 50176 >= NN)
#define CAP 5120      // per-bucket edge capacity (avg 4082, +16 sigma)
#define B1_EPB 1024   // edges per block in bucket_kernel

typedef __attribute__((ext_vector_type(8))) short bf16x8v;   // 8 bf16 (4 VGPRs)
typedef __attribute__((ext_vector_type(4))) float f32x4v;    // MFMA acc

static __device__ __forceinline__ unsigned short f2bf(float x) {
    union { float f; unsigned u; } v; v.f = x;
    unsigned r = v.u + 0x7fff + ((v.u >> 16) & 1);   // RNE
    return (unsigned short)(r >> 16);
}

// ---------------- B1: coarse bucket scatter (ushort-compressed) ----------------
__global__ __launch_bounds__(256) void bucket_kernel(const int* __restrict__ src,
                                                     const int* __restrict__ dst,
                                                     int* __restrict__ dcur,
                                                     int* __restrict__ scur,
                                                     ushort2* __restrict__ dbucket,
                                                     unsigned short* __restrict__ sbucket) {
    __shared__ int hd[NB], hsb[NB], cd[NB], cs[NB];
    int t = threadIdx.x;
    if (t < NB) { hd[t] = 0; hsb[t] = 0; }
    __syncthreads();
    int d[4], s[4];
    int e0 = blockIdx.x * B1_EPB + t;
    #pragma unroll
    for (int j = 0; j < 4; ++j) {
        int e = e0 + j * 256;
        if (e < NE) {
            d[j] = dst[e]; s[j] = src[e];
            atomicAdd(&hd[d[j] >> 8], 1);
            atomicAdd(&hsb[s[j] >> 8], 1);
        } else d[j] = -1;
    }
    __syncthreads();
    if (t < NB) {
        cd[t] = atomicAdd(&dcur[t], hd[t]);
        cs[t] = atomicAdd(&scur[t], hsb[t]);
    }
    __syncthreads();
    #pragma unroll
    for (int j = 0; j < 4; ++j) {
        if (d[j] >= 0) {
            int b = d[j] >> 8;
            int p = atomicAdd(&cd[b], 1);
            if (p < CAP) dbucket[(long)b * CAP + p] = make_ushort2((unsigned short)d[j],
                                                                   (unsigned short)s[j]);
            int bs = s[j] >> 8;
            int p2 = atomicAdd(&cs[bs], 1);
            if (p2 < CAP) sbucket[(long)bs * CAP + p2] = (unsigned short)s[j];
        }
    }
}

// ---------------- B2+B3 merged: compact CSR (ushort col) + out-degree ----------------
__global__ __launch_bounds__(256) void csr_out_kernel(const ushort2* __restrict__ dbucket,
                                                      const int* __restrict__ dcur,
                                                      const unsigned short* __restrict__ sbucket,
                                                      const int* __restrict__ scur,
                                                      int* __restrict__ row_ptr,
                                                      unsigned short* __restrict__ col,
                                                      int* __restrict__ out_cnt) {
    __shared__ int buf[256];
    __shared__ int hist[256];
    __shared__ int cur[256];
    int k = blockIdx.x, t = threadIdx.x;

    int tot = (t < NB) ? min(dcur[t], CAP) : 0;
    buf[t] = tot;
    __syncthreads();
    for (int o = 1; o < 256; o <<= 1) {
        int a = (t >= o) ? buf[t - o] : 0;
        __syncthreads();
        buf[t] += a;
        __syncthreads();
    }
    int base = (k > 0) ? buf[k - 1] : 0;
    int cnt = min(dcur[k], CAP);

    hist[t] = 0;
    __syncthreads();
    const ushort2* bk = dbucket + (long)k * CAP;
    for (int e = t; e < cnt; e += 256) atomicAdd(&hist[bk[e].x & 255], 1);
    __syncthreads();
    int h = hist[t];

    buf[t] = h;
    __syncthreads();
    for (int o = 1; o < 256; o <<= 1) {
        int a = (t >= o) ? buf[t - o] : 0;
        __syncthreads();
        buf[t] += a;
        __syncthreads();
    }
    int start = base + buf[t] - h;
    int id = (k << 8) + t;
    if (id < NN) row_ptr[id] = start;
    if (k == NB - 1 && t == 0) row_ptr[NN] = base + cnt;
    cur[t] = start;
    __syncthreads();

    for (int e = t; e < cnt; e += 256) {
        ushort2 p = bk[e];
        int pos = atomicAdd(&cur[p.x & 255], 1);
        col[pos] = p.y;
    }

    __syncthreads();
    hist[t] = 0;
    __syncthreads();
    int scnt = min(scur[k], CAP);
    const unsigned short* sk = sbucket + (long)k * CAP;
    for (int e = t; e < scnt; e += 256) atomicAdd(&hist[sk[e] & 255], 1);
    __syncthreads();
    if (id < NN) out_cnt[id] = hist[t];
}

// ---------------- merged node init + weight convert + embsum8 zero ----------------
__global__ __launch_bounds__(256) void initw_kernel(const float* __restrict__ cx,
                                                    const float* __restrict__ cy,
                                                    const int* __restrict__ row_ptr,
                                                    const int* __restrict__ out_cnt,
                                                    const float* __restrict__ W2,
                                                    const float* __restrict__ W3,
                                                    const float* __restrict__ W4,
                                                    const float* __restrict__ W5,
                                                    float* __restrict__ norm_s,
                                                    float* __restrict__ norm_d,
                                                    float* __restrict__ h0s,
                                                    unsigned short* __restrict__ Wt,
                                                    float* __restrict__ embsum8) {
    int bid = blockIdx.x, t = threadIdx.x;
    if (bid < NB) {
        int i = (bid << 8) + t;
        if (i < NN) {
            float id = (float)(row_ptr[i + 1] - row_ptr[i]);
            float od = (float)out_cnt[i];
            float ns = 1.0f / sqrtf(fmaxf(od, 1.0f));
            norm_s[i] = ns;
            norm_d[i] = 1.0f / sqrtf(fmaxf(id, 1.0f));
            h0s[i * 3 + 0] = id * ns;
            h0s[i * 3 + 1] = cx[i] * ns;
            h0s[i * 3 + 2] = cy[i] * ns;
        }
    } else {
        int gid = ((bid - NB) << 8) + t;     // < 65536
        int l = gid >> 14, idx = gid & 16383;
        int n = idx >> 7, k = idx & 127;
        const float* W = (l == 0) ? W2 : (l == 1) ? W3 : (l == 2) ? W4 : W5;
        Wt[gid] = f2bf(W[k * 128 + n]);
        if (gid < 1024) embsum8[gid] = 0.0f;   // 8 x 128 XCD-local colsum banks
    }
}

// ---------------- layer 1 fused: gather (F=3) + 3->128 matvec, one kernel ----------------
__global__ __launch_bounds__(256) void layer1_kernel(const int* __restrict__ row_ptr,
                                                     const unsigned short* __restrict__ col,
                                                     const float* __restrict__ h0s,
                                                     const float* __restrict__ norm_d,
                                                     const float* __restrict__ norm_s,
                                                     const float* __restrict__ W1,
                                                     const float* __restrict__ b1,
                                                     unsigned short* __restrict__ h1s) {
    __shared__ float la3[256][3];
    __shared__ float lw[3][128];
    __shared__ float lb[128];
    int t = threadIdx.x;
    int n0 = blockIdx.x << 8;
    if (t < 128) {
        lw[0][t] = W1[t]; lw[1][t] = W1[128 + t]; lw[2][t] = W1[256 + t];
        lb[t] = b1[t];
    }
    int n = n0 + t;
    if (n < NN) {
        float a0 = 0.f, a1 = 0.f, a2 = 0.f;
        int end = row_ptr[n + 1];
        for (int e = row_ptr[n]; e < end; ++e) {
            int s = col[e];
            a0 += h0s[s * 3 + 0];
            a1 += h0s[s * 3 + 1];
            a2 += h0s[s * 3 + 2];
        }
        float nd = norm_d[n];
        la3[t][0] = a0 * nd; la3[t][1] = a1 * nd; la3[t][2] = a2 * nd;
    }
    __syncthreads();
    #pragma unroll 4
    for (int i = 0; i < 128; ++i) {
        int idx = (i << 8) + t;
        int r = idx >> 7, c = idx & 127;
        int nn = n0 + r;
        if (nn < NN) {
            float v = la3[r][0] * lw[0][c] + la3[r][1] * lw[1][c]
                    + la3[r][2] * lw[2][c] + lb[c];
            h1s[((long)nn << 7) + c] = f2bf(fmaxf(v, 0.f) * norm_s[nn]);
        }
    }
}

// ---------------- FUSED hidden layer (2..4): paired dual-stream gather -> LDS -> MFMA ----
// 16 nodes/block, 4 waves, static row pairs, two independent 4-deep load
// chains (8 loads in flight, no spill). B-frags direct from L2-hot Wt.
__global__ __launch_bounds__(256) void fused_layer16_kernel(const int* __restrict__ row_ptr,
                                                            const unsigned short* __restrict__ col,
                                                            const unsigned int* __restrict__ hin,
                                                            const float* __restrict__ norm_d,
                                                            const float* __restrict__ norm_s,
                                                            const unsigned short* __restrict__ Wt,
                                                            const float* __restrict__ bias,
                                                            unsigned short* __restrict__ hout) {
    __shared__ unsigned int lA[16][68];   // bf16x2 A-tile; stride 68 dw -> 2-way banks (free)
    int t = threadIdx.x;
    int wv = t >> 6, lane = t & 63;
    int m0 = blockIdx.x << 4;             // 3125 blocks x 16 nodes == 50000 exactly

    const unsigned int* hb = hin + lane;
    #pragma unroll
    for (int half = 0; half < 2; ++half) {
        int rA = (half << 3) + wv;        // wv, 8+wv
        int rB = rA + 4;                  // 4+wv, 12+wv
        int nA = m0 + rA, nB = m0 + rB;
        int eA = row_ptr[nA], endA = row_ptr[nA + 1];
        int eB = row_ptr[nB], endB = row_ptr[nB + 1];
        float axA = 0.f, ayA = 0.f, axB = 0.f, ayB = 0.f;

        while (eA + 3 < endA && eB + 3 < endB) {
            unsigned uA[4], uB[4];
            #pragma unroll
            for (int j = 0; j < 4; ++j) uA[j] = hb[(long)col[eA + j] << 6];
            #pragma unroll
            for (int j = 0; j < 4; ++j) uB[j] = hb[(long)col[eB + j] << 6];
            #pragma unroll
            for (int j = 0; j < 4; ++j) {
                axA += __uint_as_float(uA[j] << 16);
                ayA += __uint_as_float(uA[j] & 0xffff0000u);
                axB += __uint_as_float(uB[j] << 16);
                ayB += __uint_as_float(uB[j] & 0xffff0000u);
            }
            eA += 4; eB += 4;
        }
        for (; eA + 3 < endA; eA += 4) {
            unsigned u[4];
            #pragma unroll
            for (int j = 0; j < 4; ++j) u[j] = hb[(long)col[eA + j] << 6];
            #pragma unroll
            for (int j = 0; j < 4; ++j) {
                axA += __uint_as_float(u[j] << 16);
                ayA += __uint_as_float(u[j] & 0xffff0000u);
            }
        }
        for (; eA < endA; ++eA) {
            unsigned u0 = hb[(long)col[eA] << 6];
            axA += __uint_as_float(u0 << 16);
            ayA += __uint_as_float(u0 & 0xffff0000u);
        }
        for (; eB + 3 < endB; eB += 4) {
            unsigned u[4];
            #pragma unroll
            for (int j = 0; j < 4; ++j) u[j] = hb[(long)col[eB + j] << 6];
            #pragma unroll
            for (int j = 0; j < 4; ++j) {
                axB += __uint_as_float(u[j] << 16);
                ayB += __uint_as_float(u[j] & 0xffff0000u);
            }
        }
        for (; eB < endB; ++eB) {
            unsigned u0 = hb[(long)col[eB] << 6];
            axB += __uint_as_float(u0 << 16);
            ayB += __uint_as_float(u0 & 0xffff0000u);
        }

        float ndA = norm_d[nA], ndB = norm_d[nB];
        lA[rA][lane] = (unsigned)f2bf(axA * ndA) | ((unsigned)f2bf(ayA * ndA) << 16);
        lA[rB][lane] = (unsigned)f2bf(axB * ndB) | ((unsigned)f2bf(ayB * ndB) << 16);
    }
    __syncthreads();

    // ---- GEMM phase: wave wv computes cols [wv*32, wv*32+32) ----
    int fr = lane & 15, kq = lane >> 4;
    bf16x8v a0 = *(const bf16x8v*)&lA[fr][ 0 + (kq << 2)];
    bf16x8v a1 = *(const bf16x8v*)&lA[fr][16 + (kq << 2)];
    bf16x8v a2 = *(const bf16x8v*)&lA[fr][32 + (kq << 2)];
    bf16x8v a3 = *(const bf16x8v*)&lA[fr][48 + (kq << 2)];

    float4 scv = *(const float4*)(norm_s + m0 + (kq << 2));

    #pragma unroll
    for (int j = 0; j < 2; ++j) {
        int n0 = ((wv << 1) + j) << 4;
        const unsigned short* wb = Wt + ((n0 + fr) << 7) + (kq << 3);
        f32x4v acc = {0.f, 0.f, 0.f, 0.f};
        acc = __builtin_amdgcn_mfma_f32_16x16x32_bf16(a0, *(const bf16x8v*)(wb + 0),  acc, 0, 0, 0);
        acc = __builtin_amdgcn_mfma_f32_16x16x32_bf16(a1, *(const bf16x8v*)(wb + 32), acc, 0, 0, 0);
        acc = __builtin_amdgcn_mfma_f32_16x16x32_bf16(a2, *(const bf16x8v*)(wb + 64), acc, 0, 0, 0);
        acc = __builtin_amdgcn_mfma_f32_16x16x32_bf16(a3, *(const bf16x8v*)(wb + 96), acc, 0, 0, 0);

        int c = n0 + fr;
        float bv = bias[c];
        #pragma unroll
        for (int r = 0; r < 4; ++r) {
            int mr = m0 + (kq << 2) + r;
            float v = fmaxf(acc[r] + bv, 0.f);
            float sc = (r == 0) ? scv.x : (r == 1) ? scv.y : (r == 2) ? scv.z : scv.w;
            hout[((long)mr << 7) + c] = f2bf(v * sc);
        }
    }
}

// ---------------- layer-5 gather: dual aggregation into bf16 aggb ----------------
__global__ __launch_bounds__(256) void gather_bf16_kernel(const int* __restrict__ row_ptr,
                                                          const unsigned short* __restrict__ col,
                                                          const unsigned int* __restrict__ hs2,
                                                          const float* __restrict__ norm_d,
                                                          unsigned int* __restrict__ aggb2) {
    int t = threadIdx.x;
    int wave = t >> 6;
    int lane = t & 63;
    int n = blockIdx.x * 4 + wave;
    if (n >= NN) return;
    int beg = row_ptr[n], end = row_ptr[n + 1];
    float nd = norm_d[n];
    const unsigned int* hb = hs2 + lane;
    float ax = 0.f, ay = 0.f;
    int e = beg;
    for (; e + 7 < end; e += 8) {
        unsigned u[8];
        #pragma unroll
        for (int j = 0; j < 8; ++j) u[j] = hb[(long)col[e + j] << 6];
        #pragma unroll
        for (int j = 0; j < 8; ++j) {
            ax += __uint_as_float(u[j] << 16);
            ay += __uint_as_float(u[j] & 0xffff0000u);
        }
    }
    for (; e < end; ++e) {
        unsigned u0 = hb[(long)col[e] << 6];
        ax += __uint_as_float(u0 << 16);
        ay += __uint_as_float(u0 & 0xffff0000u);
    }
    unsigned po = (unsigned)f2bf(ax * nd) | ((unsigned)f2bf(ay * nd) << 16);
    aggb2[(n << 6) + lane] = po;
}

// ---------------- layer-5 GEMM via MFMA (fp32 out + colsum into 8 XCD banks) ----------------
__global__ __launch_bounds__(256) void gemm_mfma_kernel(const unsigned short* __restrict__ aggb,
                                                        const unsigned short* __restrict__ Wt,
                                                        const float* __restrict__ bias,
                                                        float* __restrict__ out_f32,
                                                        float* __restrict__ embsum8) {
    __shared__ unsigned short ldsw[128][136];
    __shared__ float ldscol[4][4][128];

    int t = threadIdx.x;
    int wv = t >> 6, lane = t & 63;
    int fr = lane & 15, kq = lane >> 4;
    int m0 = blockIdx.x * 64 + wv * 16;

    #pragma unroll
    for (int i = 0; i < 8; ++i) {
        int idx = t + 256 * i;
        int r = idx >> 4;
        int c8 = (idx & 15) << 3;
        *(bf16x8v*)(&ldsw[r][c8]) = *(const bf16x8v*)(Wt + (r << 7) + c8);
    }

    int mrow = m0 + fr;
    long abase = (long)((mrow < NN) ? mrow : 0) << 7;
    bf16x8v a0 = *(const bf16x8v*)(aggb + abase + 0  + kq * 8);
    bf16x8v a1 = *(const bf16x8v*)(aggb + abase + 32 + kq * 8);
    bf16x8v a2 = *(const bf16x8v*)(aggb + abase + 64 + kq * 8);
    bf16x8v a3 = *(const bf16x8v*)(aggb + abase + 96 + kq * 8);

    __syncthreads();

    #pragma unroll
    for (int nt = 0; nt < 8; ++nt) {
        int n0 = nt << 4;
        f32x4v acc = {0.f, 0.f, 0.f, 0.f};
        acc = __builtin_amdgcn_mfma_f32_16x16x32_bf16(a0, *(const bf16x8v*)(&ldsw[n0 + fr][0  + kq * 8]), acc, 0, 0, 0);
        acc = __builtin_amdgcn_mfma_f32_16x16x32_bf16(a1, *(const bf16x8v*)(&ldsw[n0 + fr][32 + kq * 8]), acc, 0, 0, 0);
        acc = __builtin_amdgcn_mfma_f32_16x16x32_bf16(a2, *(const bf16x8v*)(&ldsw[n0 + fr][64 + kq * 8]), acc, 0, 0, 0);
        acc = __builtin_amdgcn_mfma_f32_16x16x32_bf16(a3, *(const bf16x8v*)(&ldsw[n0 + fr][96 + kq * 8]), acc, 0, 0, 0);

        int c = n0 + fr;
        float bv = bias[c];
        float cs = 0.f;
        #pragma unroll
        for (int r = 0; r < 4; ++r) {
            int mr = m0 + kq * 4 + r;
            if (mr < NN) {
                float v = fmaxf(acc[r] + bv, 0.f);
                out_f32[((long)mr << 7) + c] = v;
                cs += v;
            }
        }
        ldscol[wv][kq][c] = cs;
    }

    __syncthreads();
    if (t < 128) {
        float s = 0.f;
        #pragma unroll
        for (int w = 0; w < 4; ++w)
            #pragma unroll
            for (int q = 0; q < 4; ++q)
                s += ldscol[w][q][t];
        atomicAdd(&embsum8[((blockIdx.x & 7) << 7) + t], s);
    }
}

// ---------------- head MLP (sums the 8 embsum banks) ----------------
__global__ __launch_bounds__(128) void head_kernel(const float* __restrict__ embsum8,
                                                   const float* __restrict__ Wl1,
                                                   const float* __restrict__ bl1,
                                                   const float* __restrict__ Wl2,
                                                   const float* __restrict__ bl2,
                                                   float* __restrict__ d_out) {
    __shared__ float emb[128];
    __shared__ float hemb[64];
    int t = threadIdx.x;
    float e = 0.f;
    #pragma unroll
    for (int j = 0; j < 8; ++j) e += embsum8[(j << 7) + t];
    e *= (1.0f / (float)NN);
    emb[t] = e;
    d_out[1 + t] = e;
    __syncthreads();
    if (t < 64) {
        float acc = bl1[t];
        for (int k = 0; k < 128; ++k)
            acc += emb[k] * Wl1[k * 64 + t];
        hemb[t] = fmaxf(acc, 0.f);
    }
    __syncthreads();
    if (t == 0) {
        float acc = bl2[0];
        for (int j = 0; j < 64; ++j)
            acc += hemb[j] * Wl2[j];
        d_out[0] = 1.0f / (1.0f + expf(-acc));
    }
}

extern "C" void kernel_launch(void* const* d_in, const int* in_sizes, int n_in,
                              void* d_out, int out_size, void* d_ws, size_t ws_size,
                              hipStream_t stream) {
    const float* cx  = (const float*)d_in[0];
    const float* cy  = (const float*)d_in[1];
    const float* W1  = (const float*)d_in[2];
    const float* b1  = (const float*)d_in[3];
    const float* W2  = (const float*)d_in[4];
    const float* b2  = (const float*)d_in[5];
    const float* W3  = (const float*)d_in[6];
    const float* b3  = (const float*)d_in[7];
    const float* W4  = (const float*)d_in[8];
    const float* b4  = (const float*)d_in[9];
    const float* W5  = (const float*)d_in[10];
    const float* b5  = (const float*)d_in[11];
    const float* Wl1 = (const float*)d_in[12];
    const float* bl1 = (const float*)d_in[13];
    const float* Wl2 = (const float*)d_in[14];
    const float* bl2 = (const float*)d_in[15];
    const int*   src = (const int*)d_in[16];
    const int*   dst = (const int*)d_in[17];

    float* out = (float*)d_out;
    float* h_out = out + 129;

    // workspace layout (float-index units)
    float* ws       = (float*)d_ws;
    float* norm_s   = ws;                                   // N
    float* norm_d   = ws + NN;                              // N
    int*   out_cnt  = (int*)(ws + 2 * NN);                  // N
    int*   row_ptr  = (int*)(ws + 3 * NN);                  // N+1
    unsigned short* hsA = (unsigned short*)(ws + 4 * NN + 64);    // 128N bf16
    unsigned short* hsB = (unsigned short*)(ws + 68 * NN + 64);   // 128N bf16
    unsigned short* col = (unsigned short*)(ws + 132 * NN + 64);  // NE ushort
    float* h0s      = ws + 148 * NN + 64;                   // 3N
    unsigned short* Wt = (unsigned short*)(ws + 154 * NN + 64);   // 4*16384 bf16
    float* embsum8  = ws + 154 * NN + 64 + 32768;           // 8*128
    int*   dcur     = (int*)(ws + 154 * NN + 34112);        // NB
    int*   scur     = dcur + NB;                            // NB
    ushort2* dbucket = (ushort2*)(ws + 154 * NN + 34560);   // NB*CAP ushort2
    unsigned short* sbucket = (unsigned short*)(ws + 154 * NN + 34560 + NB * CAP);

    // 1. two-level bucket CSR build (atomic-light, ushort-compressed)
    hipMemsetAsync(dcur, 0, 2 * NB * sizeof(int), stream);
    bucket_kernel<<<(NE + B1_EPB - 1) / B1_EPB, 256, 0, stream>>>(src, dst, dcur, scur,
                                                                  dbucket, sbucket);
    csr_out_kernel<<<NB, 256, 0, stream>>>(dbucket, dcur, sbucket, scur,
                                           row_ptr, col, out_cnt);

    // 2. norms + scaled h0 + weight convert + embsum8 zero (merged)
    initw_kernel<<<NB + 256, 256, 0, stream>>>(cx, cy, row_ptr, out_cnt,
                                               W2, W3, W4, W5,
                                               norm_s, norm_d, h0s, Wt, embsum8);

    // 3. layer 1 (F_in = 3), single fused kernel -> hsA
    layer1_kernel<<<(NN + 255) / 256, 256, 0, stream>>>(row_ptr, col, h0s,
                                                        norm_d, norm_s, W1, b1, hsA);

    // 4. layers 2..4: fused dual-stream gather + MFMA (hsA -> hsB -> hsA -> hsB)
    const float* bs[3] = {b2, b3, b4};
    unsigned short* hcur = hsA;
    unsigned short* hnxt = hsB;
    for (int l = 0; l < 3; ++l) {
        fused_layer16_kernel<<<NN / 16, 256, 0, stream>>>(
            row_ptr, col, (const unsigned int*)hcur, norm_d, norm_s,
            Wt + l * 16384, bs[l], hnxt);
        unsigned short* tmp = hcur; hcur = hnxt; hnxt = tmp;
    }

    // 5. layer 5: proven split path (gather hsB -> aggb in hsA; MFMA -> fp32 + colsum)
    gather_bf16_kernel<<<(NN + 3) / 4, 256, 0, stream>>>(row_ptr, col,
                                                         (const unsigned int*)hcur,
                                                         norm_d,
                                                         (unsigned int*)hnxt);
    gemm_mfma_kernel<<<(NN + 63) / 64, 256, 0, stream>>>(hnxt, Wt + 3 * 16384, b5,
                                                         h_out, embsum8);

    // 6. head
    head_kernel<<<1, 128, 0, stream>>>(embsum8, Wl1, bl1, Wl2, bl2, out);
}